// Round 11
// baseline (6708.104 us; speedup 1.0000x reference)
//
#include <hip/hip_runtime.h>
#include <math.h>

#define D_ 1024
#define N_ 64
#define L_ 4
#define DCONV_ 4
#define KL_ 4
#define V_ 32000
#define B_ 2
#define S_ 1024
#define T_ (B_*S_)
#define GAMMA_ 0.01f
#define DT_ 0.1f
#define ALPHA_ 0.1f
#define SCALE_ 0.5f          /* 1/sqrt(L), L=4 */
#define EPS_ 1e-8f
#define NEUMANN_ITERS 6      /* ||A||~0.1 -> trunc err ~1e-7 << bf16-split noise */

typedef __attribute__((ext_vector_type(8))) short bf16x8;
typedef __attribute__((ext_vector_type(4))) float f32x4;

typedef __attribute__((address_space(1))) unsigned int gu32;
typedef __attribute__((address_space(3))) unsigned int lu32;

// async global->LDS, 16B per lane; ldst must be wave-uniform (HW adds lane*16)
__device__ inline void gld_lds16(const void* gsrc, void* ldst) {
    __builtin_amdgcn_global_load_lds((const gu32*)gsrc, (lu32*)ldst, 16, 0, 0);
}

__device__ inline unsigned short bf_hi(float x) {
    union { float f; unsigned u; } c; c.f = x;
    unsigned r = c.u + 0x7fffu + ((c.u >> 16) & 1u);
    return (unsigned short)(r >> 16);
}
__device__ inline float bf_tof(unsigned short h) {
    union { float f; unsigned u; } c; c.u = ((unsigned)h) << 16; return c.f;
}
__device__ inline f32x4 fz4() { f32x4 v; v[0]=0.f; v[1]=0.f; v[2]=0.f; v[3]=0.f; return v; }

// ---------------------------------------------------------------------------
// embed: x[t][d] = complex(emb_r[tok[t]][d], emb_i[tok[t]][d])
__global__ __launch_bounds__(256) void embed_k(const int* __restrict__ tok,
    const float* __restrict__ er, const float* __restrict__ ei,
    float2* __restrict__ X)
{
    int idx = blockIdx.x * 256 + threadIdx.x;      // T_*D_
    int t = idx >> 10, d = idx & (D_ - 1);
    int v = tok[t];
    X[idx] = make_float2(er[(size_t)v * D_ + d], ei[(size_t)v * D_ + d]);
}

// ---------------------------------------------------------------------------
// A-side prep: src float2 [M][1024] row-major -> fragment-ordered bf16 planes.
// Layout: [mt][ks(32)][p(4)][c(512)][j(8)] shorts; p: 0=re_hi 1=re_lo 2=im_hi
// 3=im_lo; c = rb*64 + r16 + 16*kc (rb=(m>>4)&7, r16=m&15, kc=(d>>3)&3).
// Lane mapping at use: A-frag lane l holds (row=l&15, k = 8*(l>>4)+j).
__global__ __launch_bounds__(256) void aprep_k(const float2* __restrict__ src,
    unsigned short* __restrict__ AP)
{
    int idx = blockIdx.x * 256 + threadIdx.x;
    int m = idx >> 7, dv = idx & 127;
    int d0 = dv * 8;
    int mt = m >> 7, rb = (m >> 4) & 7, r16 = m & 15;
    int ks = dv >> 2, kc = dv & 3;
    int c = rb * 64 + r16 + 16 * kc;
    unsigned short* o = AP + (size_t)(mt * 32 + ks) * 16384 + (size_t)c * 8;
    bf16x8 rh, rl, ih, il;
#pragma unroll
    for (int j = 0; j < 8; j++) {
        float2 y = src[(size_t)m * 1024 + d0 + j];
        unsigned short hb = bf_hi(y.x);
        rh[j] = (short)hb; rl[j] = (short)bf_hi(y.x - bf_tof(hb));
        hb = bf_hi(y.y);
        ih[j] = (short)hb; il[j] = (short)bf_hi(y.y - bf_tof(hb));
    }
    *(bf16x8*)(o)         = rh;
    *(bf16x8*)(o + 4096)  = rl;
    *(bf16x8*)(o + 8192)  = ih;
    *(bf16x8*)(o + 12288) = il;
}

// ---------------------------------------------------------------------------
// B-side prep with transpose: source is [K][N] (k-major rows, n contiguous),
// output planes are [nt][ks][p(4)][c(256)][j(8)], c = (r>>4)*64 + (r&15) + 16*kc
// with r = row within the 64-wide n-tile. Reads coalesced along n.
// SRC 0: split float arrays; SRC 1: interleaved float2.
template<int SRC>
__global__ __launch_bounds__(256) void wprepT_k(
    const float* __restrict__ Br, const float* __restrict__ Bi,
    const float2* __restrict__ Bc,
    unsigned short* __restrict__ BP, int N)
{
    int nt = blockIdx.x, ks = blockIdx.y, nks = gridDim.y;
    int lane = threadIdx.x & 63, ty = threadIdx.x >> 6;
    int n = nt * 64 + lane;
    size_t rb0 = (size_t)(ks * 32 + ty * 8) * N + n;
    bf16x8 rh, rl, ih, il;
#pragma unroll
    for (int j = 0; j < 8; j++) {
        float re, im;
        if (SRC == 0) { re = Br[rb0 + (size_t)j * N]; im = Bi[rb0 + (size_t)j * N]; }
        else          { float2 v = Bc[rb0 + (size_t)j * N]; re = v.x; im = v.y; }
        unsigned short hb = bf_hi(re);
        rh[j] = (short)hb; rl[j] = (short)bf_hi(re - bf_tof(hb));
        hb = bf_hi(im);
        ih[j] = (short)hb; il[j] = (short)bf_hi(im - bf_tof(hb));
    }
    int c = (lane >> 4) * 64 + (lane & 15) + 16 * ty;
    unsigned short* o = BP + (size_t)(nt * nks + ks) * 8192 + (size_t)c * 8;
    *(bf16x8*)(o)        = rh;
    *(bf16x8*)(o + 2048) = rl;
    *(bf16x8*)(o + 4096) = ih;
    *(bf16x8*)(o + 6144) = il;
}

// ---------------------------------------------------------------------------
// B-side prep, no transpose (source row-major [R][1024], rows are output cols),
// fused Cayley epilogue: B = 2*S - I. grid = R*128/256 blocks.
__global__ __launch_bounds__(256) void wprep_cay_k(const float2* __restrict__ S,
    unsigned short* __restrict__ BP)
{
    int idx = blockIdx.x * 256 + threadIdx.x;
    int r = idx >> 7, dv = idx & 127;
    int d0 = dv * 8, ks = dv >> 2, kc = dv & 3;
    bf16x8 rh, rl, ih, il;
#pragma unroll
    for (int j = 0; j < 8; j++) {
        float2 v = S[(size_t)r * 1024 + d0 + j];
        float re = 2.f * v.x - ((r == d0 + j) ? 1.f : 0.f);
        float im = 2.f * v.y;
        unsigned short hb = bf_hi(re);
        rh[j] = (short)hb; rl[j] = (short)bf_hi(re - bf_tof(hb));
        hb = bf_hi(im);
        ih[j] = (short)hb; il[j] = (short)bf_hi(im - bf_tof(hb));
    }
    int c = ((r >> 4) & 3) * 64 + (r & 15) + 16 * kc;
    unsigned short* o = BP + (size_t)((r >> 6) * 32 + ks) * 8192 + (size_t)c * 8;
    *(bf16x8*)(o)        = rh;
    *(bf16x8*)(o + 2048) = rl;
    *(bf16x8*)(o + 4096) = ih;
    *(bf16x8*)(o + 6144) = il;
}

// ---------------------------------------------------------------------------
// Vocab W prep, no transpose (W row-major [V][1024], rows are output cols),
// same plane layout as wprepT/wprep_cay. grid = V_/2 blocks. Memory-bound,
// runs ONCE — removes the x16-redundant in-kernel conversion in vocab GEMM.
__global__ __launch_bounds__(256) void wprep_vocab_k(
    const float* __restrict__ Wr, const float* __restrict__ Wi,
    unsigned short* __restrict__ BP)
{
    int idx = blockIdx.x * 256 + threadIdx.x;
    int r = idx >> 7, dv = idx & 127;
    int d0 = dv * 8, ks = dv >> 2, kc = dv & 3;
    const float* wrp = Wr + (size_t)r * 1024 + d0;
    const float* wip = Wi + (size_t)r * 1024 + d0;
    float4 r0 = *(const float4*)wrp, r1 = *(const float4*)(wrp + 4);
    float4 i0 = *(const float4*)wip, i1 = *(const float4*)(wip + 4);
    float rr[8] = {r0.x, r0.y, r0.z, r0.w, r1.x, r1.y, r1.z, r1.w};
    float ii[8] = {i0.x, i0.y, i0.z, i0.w, i1.x, i1.y, i1.z, i1.w};
    bf16x8 rh, rl, ih, il;
#pragma unroll
    for (int j = 0; j < 8; j++) {
        unsigned short hb = bf_hi(rr[j]);
        rh[j] = (short)hb; rl[j] = (short)bf_hi(rr[j] - bf_tof(hb));
        hb = bf_hi(ii[j]);
        ih[j] = (short)hb; il[j] = (short)bf_hi(ii[j] - bf_tof(hb));
    }
    int c = ((r >> 4) & 3) * 64 + (r & 15) + 16 * kc;
    unsigned short* o = BP + (size_t)((r >> 6) * 32 + ks) * 8192 + (size_t)c * 8;
    *(bf16x8*)(o)        = rh;
    *(bf16x8*)(o + 2048) = rl;
    *(bf16x8*)(o + 4096) = ih;
    *(bf16x8*)(o + 6144) = il;
}

// ---------------------------------------------------------------------------
// Generic complex GEMM via split-bf16 MFMA, both operands pre-prepped planes.
// C[m][n] = sum_k A[m][k]*B'[n][k]  (B' rows = output columns).
// accr = ar*br, accp = ai*bi, accq = ar*bi + ai*br; re = accr-accp, im = accq.
// EPI 0: C = prod ; EPI 1: C = I - prod (Neumann/Horner step).
// NOTE: single-buffered on purpose — dbuf would cut blocks/CU 2->1 (m132
// datapoint: occupancy loss beats pipeline gain); cross-block wave overlap
// already hides staging (m114).
template<int EPI>
__global__ __launch_bounds__(256) void gemm_cmfma(
    const unsigned short* __restrict__ AP, const unsigned short* __restrict__ BP,
    float2* __restrict__ C, int K, int ldc)
{
    __shared__ __align__(16) unsigned short lds[24576];  // A 32KB + B 16KB
    const int tid = threadIdx.x, w = tid >> 6, lane = tid & 63;
    const int mt = blockIdx.x, nt = blockIdx.y, nks = K >> 5;

    f32x4 accr[2][4], accp[2][4], accq[2][4];
#pragma unroll
    for (int mi = 0; mi < 2; mi++)
#pragma unroll
        for (int ni = 0; ni < 4; ni++) {
            accr[mi][ni] = fz4(); accp[mi][ni] = fz4(); accq[mi][ni] = fz4();
        }

    for (int ks = 0; ks < nks; ks++) {
        // async DMA staging: wave-uniform LDS base + lane*16, linear order
        const unsigned short* ap = AP + (size_t)(mt * nks + ks) * 16384;
#pragma unroll
        for (int hh = 0; hh < 8; hh++) {
            int cbase = hh * 256 + w * 64;
            gld_lds16(ap + (size_t)(cbase + lane) * 8, &lds[(size_t)cbase * 8]);
        }
        const unsigned short* bp = BP + (size_t)(nt * nks + ks) * 8192;
#pragma unroll
        for (int hh = 0; hh < 4; hh++) {
            int cbase = hh * 256 + w * 64;
            gld_lds16(bp + (size_t)(cbase + lane) * 8, &lds[16384 + (size_t)cbase * 8]);
        }
        __syncthreads();   // drains vmcnt (incl. global_load_lds) + lgkm

        bf16x8 af[4][2];
#pragma unroll
        for (int p = 0; p < 4; p++)
#pragma unroll
            for (int mi = 0; mi < 2; mi++)
                af[p][mi] = *(const bf16x8*)(&lds[p * 4096 + ((w * 2 + mi) * 64 + lane) * 8]);

#pragma unroll
        for (int ni = 0; ni < 4; ni++) {
            bf16x8 b0 = *(const bf16x8*)(&lds[16384 + 0 * 2048 + (ni * 64 + lane) * 8]);
            bf16x8 b1 = *(const bf16x8*)(&lds[16384 + 1 * 2048 + (ni * 64 + lane) * 8]);
            bf16x8 b2 = *(const bf16x8*)(&lds[16384 + 2 * 2048 + (ni * 64 + lane) * 8]);
            bf16x8 b3 = *(const bf16x8*)(&lds[16384 + 3 * 2048 + (ni * 64 + lane) * 8]);
#pragma unroll
            for (int mi = 0; mi < 2; mi++) {
                f32x4 r = accr[mi][ni];      // ar*br
                r = __builtin_amdgcn_mfma_f32_16x16x32_bf16(af[0][mi], b0, r, 0, 0, 0);
                r = __builtin_amdgcn_mfma_f32_16x16x32_bf16(af[1][mi], b0, r, 0, 0, 0);
                r = __builtin_amdgcn_mfma_f32_16x16x32_bf16(af[0][mi], b1, r, 0, 0, 0);
                accr[mi][ni] = r;
                f32x4 p = accp[mi][ni];      // ai*bi
                p = __builtin_amdgcn_mfma_f32_16x16x32_bf16(af[2][mi], b2, p, 0, 0, 0);
                p = __builtin_amdgcn_mfma_f32_16x16x32_bf16(af[3][mi], b2, p, 0, 0, 0);
                p = __builtin_amdgcn_mfma_f32_16x16x32_bf16(af[2][mi], b3, p, 0, 0, 0);
                accp[mi][ni] = p;
                f32x4 q = accq[mi][ni];      // ar*bi + ai*br
                q = __builtin_amdgcn_mfma_f32_16x16x32_bf16(af[0][mi], b2, q, 0, 0, 0);
                q = __builtin_amdgcn_mfma_f32_16x16x32_bf16(af[1][mi], b2, q, 0, 0, 0);
                q = __builtin_amdgcn_mfma_f32_16x16x32_bf16(af[0][mi], b3, q, 0, 0, 0);
                q = __builtin_amdgcn_mfma_f32_16x16x32_bf16(af[2][mi], b0, q, 0, 0, 0);
                q = __builtin_amdgcn_mfma_f32_16x16x32_bf16(af[3][mi], b0, q, 0, 0, 0);
                q = __builtin_amdgcn_mfma_f32_16x16x32_bf16(af[2][mi], b1, q, 0, 0, 0);
                accq[mi][ni] = q;
            }
        }
        __syncthreads();
    }
    const int rbase = mt * 128 + w * 32;
#pragma unroll
    for (int mi = 0; mi < 2; mi++)
#pragma unroll
        for (int ni = 0; ni < 4; ni++)
#pragma unroll
            for (int r = 0; r < 4; r++) {
                int row = rbase + mi * 16 + (lane >> 4) * 4 + r;
                int col = nt * 64 + ni * 16 + (lane & 15);
                float re = accr[mi][ni][r] - accp[mi][ni][r];
                float im = accq[mi][ni][r];
                if (EPI == 1) { re = (row == col ? 1.0f : 0.0f) - re; im = -im; }
                C[(size_t)row * ldc + col] = make_float2(re, im);
            }
}

// ---------------------------------------------------------------------------
// Vocab GEMM (y * conj(W)) with |.|^2 epilogue. A from prepped planes (DMA).
//   re = ar*br + ai*bi (accr) ; im = ai*br (accp) - ar*bi (accq)
// BPREP 1: W pre-prepped planes, staged via DMA (no conversion VALU).
// BPREP 0: W split hi/lo on the fly (fallback when workspace too small).
// 2-level XCD blocking (HW round-robin: XCD = bid%8): XCD c owns mt {2c,2c+1}
// and streams all 500 vt panels (vt-major, mt-pair innermost). A working set
// 2x1.05MB -> L2-resident (A L3 traffic 8.4GB -> 17MB); B panel shared by the
// 2 consecutive blocks (L2-hot pair). Bijective: 8 XCD x 2 mt x 500 vt = 8000.
// s_setprio around the MFMA cluster (T5): 2 independent blocks/CU.
template<int BPREP>
__global__ __launch_bounds__(256) void vocab_mfma_k(
    const unsigned short* __restrict__ AP, const unsigned short* __restrict__ BPV,
    const float* __restrict__ Wr, const float* __restrict__ Wi,
    float* __restrict__ O)
{
    __shared__ __align__(16) unsigned short lds[24576];
    const int tid = threadIdx.x;
    const int w = tid >> 6, lane = tid & 63;
    int bid = blockIdx.x;                        // 8000 = 16 mt x 500 vt
    int xcd = bid & 7, i = bid >> 3;             // i in [0,1000)
    const int mtb = xcd * 2 + (i & 1);           // XCD-resident A pair
    const int vtb = i >> 1;                      // vt-major walk
    const int m0 = mtb * 128, v0 = vtb * 64;

    f32x4 accr[2][4], accp[2][4], accq[2][4];
#pragma unroll
    for (int mi = 0; mi < 2; mi++)
#pragma unroll
        for (int ni = 0; ni < 4; ni++) {
            accr[mi][ni] = fz4(); accp[mi][ni] = fz4(); accq[mi][ni] = fz4();
        }

    for (int ks = 0; ks < 32; ks++) {
        // issue async A staging first
        const unsigned short* ap = AP + (size_t)(mtb * 32 + ks) * 16384;
#pragma unroll
        for (int hh = 0; hh < 8; hh++) {
            int cbase = hh * 256 + w * 64;
            gld_lds16(ap + (size_t)(cbase + lane) * 8, &lds[(size_t)cbase * 8]);
        }
        if (BPREP == 1) {
            // stage B: pure DMA from pre-prepped planes
            const unsigned short* bp = BPV + (size_t)(vtb * 32 + ks) * 8192;
#pragma unroll
            for (int hh = 0; hh < 4; hh++) {
                int cbase = hh * 256 + w * 64;
                gld_lds16(bp + (size_t)(cbase + lane) * 8, &lds[16384 + (size_t)cbase * 8]);
            }
        } else {
            // stage B: load W fp32, split hi/lo, fragment-ordered write
            int vrow = tid >> 2, dc = tid & 3;
            const float* wrp = Wr + (size_t)(v0 + vrow) * D_ + ks * 32 + dc * 8;
            const float* wip = Wi + (size_t)(v0 + vrow) * D_ + ks * 32 + dc * 8;
            float4 r0 = *(const float4*)wrp, r1 = *(const float4*)(wrp + 4);
            float4 i0 = *(const float4*)wip, i1 = *(const float4*)(wip + 4);
            float rr[8] = {r0.x, r0.y, r0.z, r0.w, r1.x, r1.y, r1.z, r1.w};
            float ii[8] = {i0.x, i0.y, i0.z, i0.w, i1.x, i1.y, i1.z, i1.w};
            bf16x8 brh, brl, bih, bil;
#pragma unroll
            for (int j = 0; j < 8; j++) {
                unsigned short hb = bf_hi(rr[j]);
                brh[j] = (short)hb; brl[j] = (short)bf_hi(rr[j] - bf_tof(hb));
                hb = bf_hi(ii[j]);
                bih[j] = (short)hb; bil[j] = (short)bf_hi(ii[j] - bf_tof(hb));
            }
            int nb = vrow >> 4, ln = (vrow & 15) + 16 * dc;
            int bo = 16384 + (nb * 64 + ln) * 8;
            *(bf16x8*)(&lds[bo + 0 * 2048]) = brh;
            *(bf16x8*)(&lds[bo + 1 * 2048]) = brl;
            *(bf16x8*)(&lds[bo + 2 * 2048]) = bih;
            *(bf16x8*)(&lds[bo + 3 * 2048]) = bil;
        }
        __syncthreads();

        bf16x8 af[4][2];
#pragma unroll
        for (int p = 0; p < 4; p++)
#pragma unroll
            for (int mi = 0; mi < 2; mi++)
                af[p][mi] = *(const bf16x8*)(&lds[p * 4096 + ((w * 2 + mi) * 64 + lane) * 8]);

        __builtin_amdgcn_s_setprio(1);
#pragma unroll
        for (int ni = 0; ni < 4; ni++) {
            bf16x8 b0 = *(const bf16x8*)(&lds[16384 + 0 * 2048 + (ni * 64 + lane) * 8]);
            bf16x8 b1 = *(const bf16x8*)(&lds[16384 + 1 * 2048 + (ni * 64 + lane) * 8]);
            bf16x8 b2 = *(const bf16x8*)(&lds[16384 + 2 * 2048 + (ni * 64 + lane) * 8]);
            bf16x8 b3 = *(const bf16x8*)(&lds[16384 + 3 * 2048 + (ni * 64 + lane) * 8]);
#pragma unroll
            for (int mi = 0; mi < 2; mi++) {
                f32x4 r = accr[mi][ni];
                r = __builtin_amdgcn_mfma_f32_16x16x32_bf16(af[0][mi], b0, r, 0, 0, 0);
                r = __builtin_amdgcn_mfma_f32_16x16x32_bf16(af[1][mi], b0, r, 0, 0, 0);
                r = __builtin_amdgcn_mfma_f32_16x16x32_bf16(af[0][mi], b1, r, 0, 0, 0);
                r = __builtin_amdgcn_mfma_f32_16x16x32_bf16(af[2][mi], b2, r, 0, 0, 0);
                r = __builtin_amdgcn_mfma_f32_16x16x32_bf16(af[3][mi], b2, r, 0, 0, 0);
                r = __builtin_amdgcn_mfma_f32_16x16x32_bf16(af[2][mi], b3, r, 0, 0, 0);
                accr[mi][ni] = r;
                f32x4 p = accp[mi][ni];
                p = __builtin_amdgcn_mfma_f32_16x16x32_bf16(af[2][mi], b0, p, 0, 0, 0);
                p = __builtin_amdgcn_mfma_f32_16x16x32_bf16(af[3][mi], b0, p, 0, 0, 0);
                p = __builtin_amdgcn_mfma_f32_16x16x32_bf16(af[2][mi], b1, p, 0, 0, 0);
                accp[mi][ni] = p;
                f32x4 q = accq[mi][ni];
                q = __builtin_amdgcn_mfma_f32_16x16x32_bf16(af[0][mi], b2, q, 0, 0, 0);
                q = __builtin_amdgcn_mfma_f32_16x16x32_bf16(af[1][mi], b2, q, 0, 0, 0);
                q = __builtin_amdgcn_mfma_f32_16x16x32_bf16(af[0][mi], b3, q, 0, 0, 0);
                accq[mi][ni] = q;
            }
        }
        __builtin_amdgcn_s_setprio(0);
        __syncthreads();
    }
    const int rbase = m0 + w * 32;
#pragma unroll
    for (int mi = 0; mi < 2; mi++)
#pragma unroll
        for (int ni = 0; ni < 4; ni++)
#pragma unroll
            for (int r = 0; r < 4; r++) {
                int row = rbase + mi * 16 + (lane >> 4) * 4 + r;
                int col = v0 + ni * 16 + (lane & 15);
                float re = accr[mi][ni][r];
                float im = accp[mi][ni][r] - accq[mi][ni][r];
                O[(size_t)row * V_ + col] = re * re + im * im;
            }
}

// ---------------------------------------------------------------------------
// causal depthwise conv: U[t][d] = sum_k w[d][k] * u[t-k][d]
__global__ __launch_bounds__(256) void conv_k(const float2* __restrict__ UZ,
    const float* __restrict__ cwr, const float* __restrict__ cwi,
    float2* __restrict__ U)
{
    int idx = blockIdx.x * 256 + threadIdx.x;    // T_*D_
    int d = idx & (D_ - 1);
    int t = idx >> 10;
    int s = t & (S_ - 1);
    float2 acc = make_float2(0.f, 0.f);
#pragma unroll
    for (int k = 0; k < DCONV_; k++) {
        if (s >= k) {
            float2 u = UZ[(size_t)(t - k) * (2 * D_) + d];
            float wr = cwr[d * DCONV_ + k], wi = cwi[d * DCONV_ + k];
            acc.x += wr * u.x - wi * u.y;
            acc.y += wr * u.y + wi * u.x;
        }
    }
    U[idx] = acc;
}

// ---------------------------------------------------------------------------
// SSM scan. One 64-lane wave per (b,d); lane = state index n.
__global__ __launch_bounds__(256) void scan_k(float2* UY,
    const float2* __restrict__ UZ,
    const float* __restrict__ alr, const float* __restrict__ aim,
    const float* __restrict__ bmr, const float* __restrict__ bmi,
    const float* __restrict__ cmr, const float* __restrict__ cmi)
{
    int wid = blockIdx.x * 4 + (threadIdx.x >> 6);   // 0..B_*D_-1
    int lane = threadIdx.x & 63;
    int b = wid >> 10, d = wid & (D_ - 1);
    int pi = d * N_ + lane;

    float ar = alr[pi], ai = aim[pi];
    float mag = expf(-expf(ar));
    float dsn, dcs; sincosf(ai, &dsn, &dcs);
    float der = mag * dcs, dei = mag * dsn;
    float br = bmr[pi], bi = bmi[pi];
    float cr = cmr[pi], ci = cmi[pi];

    float hr = 0.f, hi = 0.f;
    float2* ucol = UY + (size_t)b * S_ * D_ + d;
    const float2* zcol = UZ + (size_t)b * S_ * (2 * D_) + D_ + d;

    for (int t = 0; t < S_; t++) {
        float2 u = ucol[(size_t)t * D_];
        float nhr = der * hr - dei * hi + br * u.x - bi * u.y;
        float nhi = der * hi + dei * hr + br * u.y + bi * u.x;
        hr = nhr; hi = nhi;
        float vr = cr * hr - ci * hi;
        float vi = cr * hi + ci * hr;
#pragma unroll
        for (int m = 32; m > 0; m >>= 1) {
            vr += __shfl_xor(vr, m);
            vi += __shfl_xor(vi, m);
        }
        if (lane == 0) {
            float2 z = zcol[(size_t)t * (2 * D_)];
            float g = 1.0f / (1.0f + expf(-z.x));
            float gr = z.x * g, gi = z.y * g;
            ucol[(size_t)t * D_] = make_float2(vr * gr - vi * gi, vr * gi + vi * gr);
        }
    }
}

// ---------------------------------------------------------------------------
// proj[t][k] = sum_d conj(lind[k][d]) * BR[t][d]
__global__ __launch_bounds__(256) void lproj_k(const float2* __restrict__ BR,
    const float* __restrict__ lr, const float* __restrict__ li,
    float2* __restrict__ PROJ)
{
    int wid = blockIdx.x * 4 + (threadIdx.x >> 6);   // 0..T_*KL_-1
    int lane = threadIdx.x & 63;
    int t = wid >> 2, k = wid & 3;
    float sr = 0.f, si = 0.f;
    for (int d = lane; d < D_; d += 64) {
        float2 v = BR[(size_t)t * D_ + d];
        float a = lr[k * D_ + d], bb = li[k * D_ + d];
        sr += a * v.x + bb * v.y;       // conj(l) * v
        si += a * v.y - bb * v.x;
    }
#pragma unroll
    for (int m = 32; m > 0; m >>= 1) {
        sr += __shfl_xor(sr, m);
        si += __shfl_xor(si, m);
    }
    if (lane == 0) PROJ[t * KL_ + k] = make_float2(sr, si);
}

// BR[t][d] -= GAMMA * sum_k lind[k][d] * proj[t][k]
__global__ __launch_bounds__(256) void lupd_k(float2* BR,
    const float* __restrict__ lr, const float* __restrict__ li,
    const float2* __restrict__ PROJ)
{
    int idx = blockIdx.x * 256 + threadIdx.x;
    int t = idx >> 10, d = idx & (D_ - 1);
    float ax = 0.f, ay = 0.f;
#pragma unroll
    for (int k = 0; k < KL_; k++) {
        float2 p = PROJ[t * KL_ + k];
        float a = lr[k * D_ + d], bb = li[k * D_ + d];
        ax += a * p.x - bb * p.y;
        ay += a * p.y + bb * p.x;
    }
    float2 v = BR[idx];
    BR[idx] = make_float2(v.x - GAMMA_ * ax, v.y - GAMMA_ * ay);
}

// partial column sums of |BR|^2 over s-chunks of 64
__global__ __launch_bounds__(256) void diagp_k(const float2* __restrict__ BR,
    float* __restrict__ DIAGP)
{
    int d = blockIdx.x * 256 + threadIdx.x;
    int sc = blockIdx.y, b = blockIdx.z;
    float acc = 0.f;
    for (int s = sc * 64; s < sc * 64 + 64; s++) {
        float2 v = BR[((size_t)b * S_ + s) * D_ + d];
        acc += v.x * v.x + v.y * v.y;
    }
    DIAGP[(b * 16 + sc) * D_ + d] = acc;
}

__global__ __launch_bounds__(256) void cond_k(const float* __restrict__ DIAGP,
    const float* __restrict__ theta, int l, float2* __restrict__ PHASE)
{
    __shared__ float rmx[256], rmn[256];
    int b = blockIdx.x, tid = threadIdx.x;
    float mx = -1e30f, mn = 1e30f;
    for (int d = tid; d < D_; d += 256) {
        float s = 0.f;
        for (int sc = 0; sc < 16; sc++) s += DIAGP[(b * 16 + sc) * D_ + d];
        s *= (1.0f / S_);
        mx = fmaxf(mx, s); mn = fminf(mn, s);
    }
    rmx[tid] = mx; rmn[tid] = mn; __syncthreads();
    for (int o = 128; o > 0; o >>= 1) {
        if (tid < o) {
            rmx[tid] = fmaxf(rmx[tid], rmx[tid + o]);
            rmn[tid] = fminf(rmn[tid], rmn[tid + o]);
        }
        __syncthreads();
    }
    if (tid == 0) {
        float cond = rmx[0] / (rmn[0] + EPS_);
        float th = theta[l];
        PHASE[b] = (cond > 100.0f) ? make_float2(cosf(th), sinf(th))
                                   : make_float2(1.0f, 0.0f);
    }
}

// x += SCALE * BR * phase[b]
__global__ __launch_bounds__(256) void xupd_k(float2* X,
    const float2* __restrict__ BR, const float2* __restrict__ PHASE)
{
    int idx = blockIdx.x * 256 + threadIdx.x;
    int b = idx >> 20;                              // S_*D_ = 2^20
    float2 ph = PHASE[b];
    float2 v = BR[idx];
    float2 x = X[idx];
    x.x += SCALE_ * (v.x * ph.x - v.y * ph.y);
    x.y += SCALE_ * (v.x * ph.y + v.y * ph.x);
    X[idx] = x;
}

// ---------------------------------------------------------------------------
// AOP = 0.5j*DT*Hh, Hh = 0.5*(P + P^H)
__global__ __launch_bounds__(256) void aop_k(const float* __restrict__ Pr,
    const float* __restrict__ Pi, float2* __restrict__ AOP)
{
    int idx = blockIdx.x * 256 + threadIdx.x;   // D_*D_
    int d = idx >> 10, e = idx & (D_ - 1);
    float hrv = 0.5f * (Pr[(size_t)d * D_ + e] + Pr[(size_t)e * D_ + d]);
    float hiv = 0.5f * (Pi[(size_t)d * D_ + e] - Pi[(size_t)e * D_ + d]);
    AOP[idx] = make_float2(-0.5f * DT_ * hiv, 0.5f * DT_ * hrv);
}

__global__ __launch_bounds__(256) void initI_k(float2* __restrict__ Smat)
{
    int idx = blockIdx.x * 256 + threadIdx.x;
    int d = idx >> 10, e = idx & (D_ - 1);
    Smat[idx] = make_float2(d == e ? 1.0f : 0.0f, 0.0f);
}

// phase rotation by alpha*|y|^2 fused with RMS norm (rotation preserves |y|^2)
__global__ __launch_bounds__(256) void norm_k(float2* Y, const float* __restrict__ nw)
{
    __shared__ float red[256];
    int t = blockIdx.x, tid = threadIdx.x;
    float2 v[4];
    float part = 0.f;
#pragma unroll
    for (int i = 0; i < 4; i++) {
        int d = tid + 256 * i;
        float2 y = Y[(size_t)t * D_ + d];
        float m = y.x * y.x + y.y * y.y;
        part += m;
        float sn, cs; sincosf(ALPHA_ * m, &sn, &cs);
        v[i] = make_float2(y.x * cs - y.y * sn, y.x * sn + y.y * cs);
    }
    red[tid] = part; __syncthreads();
    for (int o = 128; o > 0; o >>= 1) {
        if (tid < o) red[tid] += red[tid + o];
        __syncthreads();
    }
    float inv = 1.0f / sqrtf(red[0] / D_ + EPS_);
#pragma unroll
    for (int i = 0; i < 4; i++) {
        int d = tid + 256 * i;
        float sc = nw[d] * inv;
        Y[(size_t)t * D_ + d] = make_float2(v[i].x * sc, v[i].y * sc);
    }
}

// ---------------------------------------------------------------------------
extern "C" void kernel_launch(void* const* d_in, const int* in_sizes, int n_in,
                              void* d_out, int out_size, void* d_ws, size_t ws_size,
                              hipStream_t stream)
{
    const float* emb_r     = (const float*)d_in[0];
    const float* emb_i     = (const float*)d_in[1];
    const float* in_proj_r = (const float*)d_in[2];
    const float* in_proj_i = (const float*)d_in[3];
    const float* conv_w_r  = (const float*)d_in[4];
    const float* conv_w_i  = (const float*)d_in[5];
    const float* A_logr    = (const float*)d_in[6];
    const float* A_imag    = (const float*)d_in[7];
    const float* Bm_r      = (const float*)d_in[8];
    const float* Bm_i      = (const float*)d_in[9];
    const float* Cm_r      = (const float*)d_in[10];
    const float* Cm_i      = (const float*)d_in[11];
    const float* out_proj_r= (const float*)d_in[12];
    const float* out_proj_i= (const float*)d_in[13];
    const float* lind_r    = (const float*)d_in[14];
    const float* lind_i    = (const float*)d_in[15];
    const float* quat_theta= (const float*)d_in[16];
    const float* prop_H_r  = (const float*)d_in[17];
    const float* prop_H_i  = (const float*)d_in[18];
    const float* norm_w    = (const float*)d_in[19];
    const float* W_out_r   = (const float*)d_in[20];
    const float* W_out_i   = (const float*)d_in[21];
    const int*   tok       = (const int*)d_in[22];
    float* out = (float*)d_out;

    char* ws = (char*)d_ws;
    const size_t MB = 1024 * 1024;
    float2* X  = (float2*)(ws);                       // 16 MB
    float2* UZ = (float2*)(ws + 16 * MB);             // 32 MB
    float2* U  = (float2*)(ws + 48 * MB);             // 16 MB
    unsigned short* XP = (unsigned short*)(ws + 64 * MB);  // 16 MB (A planes)
    unsigned short* WP = (unsigned short*)(ws + 80 * MB);  // 16 MB (B planes)
    float2* PROJ  = (float2*)(ws + 96 * MB);
    float*  DIAGP = (float*)(ws + 96 * MB + 64 * 1024);
    float2* PHASE = (float2*)(ws + 96 * MB + 192 * 1024);
    unsigned short* WPV = (unsigned short*)(ws + 100 * MB);  // 262 MB vocab planes
    const size_t WPV_NEED = 100 * MB + (size_t)V_ * D_ * 4 * 2;  // ~362 MB
    const bool use_wprep = (ws_size >= WPV_NEED);   // constant across calls ->
                                                    // graph-capture safe
    // final-stage aliases inside UZ (quarters of 32MB; each D*D float2 = 8MB):
    float2* AOP = UZ;
    float2* SM  = UZ + (size_t)D_ * D_;
    float2* TM  = UZ + 2 * (size_t)D_ * D_;
    unsigned short* AOPP = (unsigned short*)(UZ + 3 * (size_t)D_ * D_); // 8MB planes
    float2* BR = UZ;   // branch output during layer loop

    int TD = T_ * D_;

    embed_k<<<TD / 256, 256, 0, stream>>>(tok, emb_r, emb_i, X);

    for (int l = 0; l < L_; l++) {
        aprep_k<<<T_ / 2, 256, 0, stream>>>(X, XP);                       // M=2048
        wprepT_k<0><<<dim3(32, 32), 256, 0, stream>>>(
            in_proj_r + (size_t)l * D_ * 2 * D_, in_proj_i + (size_t)l * D_ * 2 * D_,
            nullptr, WP, 2 * D_);
        gemm_cmfma<0><<<dim3(T_ / 128, 32), 256, 0, stream>>>(XP, WP, UZ, D_, 2 * D_);
        conv_k<<<TD / 256, 256, 0, stream>>>(
            UZ, conv_w_r + (size_t)l * D_ * DCONV_, conv_w_i + (size_t)l * D_ * DCONV_, U);
        scan_k<<<B_ * D_ / 4, 256, 0, stream>>>(
            U, UZ,
            A_logr + (size_t)l * D_ * N_, A_imag + (size_t)l * D_ * N_,
            Bm_r + (size_t)l * D_ * N_, Bm_i + (size_t)l * D_ * N_,
            Cm_r + (size_t)l * D_ * N_, Cm_i + (size_t)l * D_ * N_);
        aprep_k<<<T_ / 2, 256, 0, stream>>>(U, XP);
        wprepT_k<0><<<dim3(16, 32), 256, 0, stream>>>(
            out_proj_r + (size_t)l * D_ * D_, out_proj_i + (size_t)l * D_ * D_,
            nullptr, WP, D_);
        gemm_cmfma<0><<<dim3(T_ / 128, 16), 256, 0, stream>>>(XP, WP, BR, D_, D_);
        lproj_k<<<T_ * KL_ / 4, 256, 0, stream>>>(
            BR, lind_r + (size_t)l * KL_ * D_, lind_i + (size_t)l * KL_ * D_, PROJ);
        lupd_k<<<TD / 256, 256, 0, stream>>>(
            BR, lind_r + (size_t)l * KL_ * D_, lind_i + (size_t)l * KL_ * D_, PROJ);
        diagp_k<<<dim3(D_ / 256, 16, B_), 256, 0, stream>>>(BR, DIAGP);
        cond_k<<<B_, 256, 0, stream>>>(DIAGP, quat_theta, l, PHASE);
        xupd_k<<<TD / 256, 256, 0, stream>>>(X, BR, PHASE);
    }

    // final propagator: S = (I+A)^{-1} via Neumann/Horner, C = 2S - I (Cayley)
    aop_k<<<D_ * D_ / 256, 256, 0, stream>>>(prop_H_r, prop_H_i, AOP);
    aprep_k<<<D_ / 2, 256, 0, stream>>>(AOP, AOPP);                       // M=1024
    initI_k<<<D_ * D_ / 256, 256, 0, stream>>>(SM);
    for (int it = 0; it < NEUMANN_ITERS; it++) {
        float2* src = (it & 1) ? TM : SM;
        float2* dst = (it & 1) ? SM : TM;
        wprepT_k<1><<<dim3(16, 32), 256, 0, stream>>>(nullptr, nullptr, src, WP, D_);
        gemm_cmfma<1><<<dim3(D_ / 128, 16), 256, 0, stream>>>(AOPP, WP, dst, D_, D_);
    }
    aprep_k<<<T_ / 2, 256, 0, stream>>>(X, XP);
    wprep_cay_k<<<D_ / 2, 256, 0, stream>>>(SM, WP);
    gemm_cmfma<0><<<dim3(T_ / 128, 16), 256, 0, stream>>>(XP, WP, U, D_, D_);

    norm_k<<<T_, 256, 0, stream>>>(U, norm_w);

    aprep_k<<<T_ / 2, 256, 0, stream>>>(U, XP);
    if (use_wprep) {
        wprep_vocab_k<<<V_ / 2, 256, 0, stream>>>(W_out_r, W_out_i, WPV);
        vocab_mfma_k<1><<<8000, 256, 0, stream>>>(XP, WPV, W_out_r, W_out_i, out);
    } else {
        vocab_mfma_k<0><<<8000, 256, 0, stream>>>(XP, nullptr, W_out_r, W_out_i, out);
    }
}